// Round 1
// baseline (278.329 us; speedup 1.0000x reference)
//
#include <hip/hip_runtime.h>

#define NN 50000
#define CAP 32          // per-node bin capacity; overflow handled correctly
#define OVF_CAP 4096
#define SHARD_W 12500   // node-quarter width (4 quarters cover NN)
#define NCH 64          // edge chunks per relation for counting sort

__device__ __forceinline__ unsigned short f2bf(float f) {
    unsigned u = __float_as_uint(f);
    u += 0x7fffu + ((u >> 16) & 1u);           // round-to-nearest-even
    return (unsigned short)(u >> 16);
}
__device__ __forceinline__ float bf2f(unsigned short u) {
    return __uint_as_float(((unsigned)u) << 16);
}

// Fused init: zero ovf_cnt AND convert x -> bf16. (deg is now fully written
// by prefix_pass — no pre-zero needed.)
__global__ __launch_bounds__(256) void init_fuse(
    const float* __restrict__ in, unsigned short* __restrict__ out, int n4,
    int* __restrict__ zbuf, int nint)
{
    int stride = gridDim.x * blockDim.x;
    int id0 = blockIdx.x * blockDim.x + threadIdx.x;
    for (int i = id0; i < n4; i += stride) {
        float4 v = ((const float4*)in)[i];
        ushort4 o;
        o.x = f2bf(v.x); o.y = f2bf(v.y); o.z = f2bf(v.z); o.w = f2bf(v.w);
        ((ushort4*)out)[i] = o;
    }
    for (int i = id0; i < nint; i += stride) zbuf[i] = 0;
}

// ---- Counting-sort binning (replaces atomic bin_fill; R12) ----
// Old single-pass bin_fill hit a 71us plateau insensitive to sharding/NT/
// alignment/LDS-staging (R4-R11) => the wall is the 1.6M device-scope global
// atomicAdds (fabric RMW), not traffic. This 3-pass scheme uses ONLY LDS
// atomics (CU-local banks) + one rare global atomic for overflow.
//
// Block decode (grid = 2 rel * NCH chunks * 4 quarters = 512):
//   quarter = bid & 3, chunk = (bid>>2) & (NCH-1), rel = bid >> 8.

__global__ __launch_bounds__(256) void count_pass(
    const int* __restrict__ ei0, int E0,
    const int* __restrict__ ei1, int E1,
    unsigned char* __restrict__ cnt)            // [2][NCH][NN] (aliases bins)
{
    __shared__ int lcnt[SHARD_W];               // 48.8 KB
    int q   = blockIdx.x & 3;
    int c   = (blockIdx.x >> 2) & (NCH - 1);
    int rel = blockIdx.x >> 8;
    const int* ei = rel ? ei1 : ei0;
    int E         = rel ? E1  : E0;
    int ce = (E + NCH - 1) / NCH;
    int lo = c * ce;
    int hi = min(lo + ce, E);
    int nlo = q * SHARD_W;

    for (int i = threadIdx.x; i < SHARD_W; i += 256) lcnt[i] = 0;
    __syncthreads();
    for (int t = lo + threadIdx.x; t < hi; t += 256) {
        int loc = ei[E + t] - nlo;
        if ((unsigned)loc < (unsigned)SHARD_W) atomicAdd(&lcnt[loc], 1);
    }
    __syncthreads();
    unsigned char* dst = cnt + ((size_t)(rel * NCH + c)) * NN + nlo;
    for (int i = threadIdx.x; i < SHARD_W / 4; i += 256) {
        uchar4 v;
        v.x = (unsigned char)min(lcnt[4 * i + 0], 255);
        v.y = (unsigned char)min(lcnt[4 * i + 1], 255);
        v.z = (unsigned char)min(lcnt[4 * i + 2], 255);
        v.w = (unsigned char)min(lcnt[4 * i + 3], 255);
        ((uchar4*)dst)[i] = v;
    }
}

// Per-node running sum over chunks: exact deg (int) + saturated u8 bases.
// Saturation is safe: only base values < CAP=32 ever index bins; any
// slot >= CAP goes to the overflow list regardless.
__global__ __launch_bounds__(256) void prefix_pass(
    const unsigned char* __restrict__ cnt,      // [2][NCH][NN]
    unsigned char* __restrict__ bases,          // [2][NCH][NN] (aliases aggb)
    int* __restrict__ deg)                      // [2*NN]
{
    int t = blockIdx.x * 256 + threadIdx.x;     // one thread per 4 nodes per rel
    if (t >= 2 * (NN / 4)) return;
    int rel = t / (NN / 4);
    int n4  = (t % (NN / 4)) * 4;

    unsigned run0 = 0, run1 = 0, run2 = 0, run3 = 0;
    #pragma unroll
    for (int c = 0; c < NCH; c++) {
        size_t idx = ((size_t)(rel * NCH + c)) * NN + n4;
        unsigned v = *(const unsigned*)&cnt[idx];
        unsigned b0 = min(run0, 255u), b1 = min(run1, 255u);
        unsigned b2 = min(run2, 255u), b3 = min(run3, 255u);
        *(unsigned*)&bases[idx] = b0 | (b1 << 8) | (b2 << 16) | (b3 << 24);
        run0 += v & 255u;
        run1 += (v >> 8) & 255u;
        run2 += (v >> 16) & 255u;
        run3 += (v >> 24);
    }
    *(int4*)&deg[rel * NN + n4] = make_int4(run0, run1, run2, run3);
}

__global__ __launch_bounds__(256) void place_pass(
    const int* __restrict__ ei0, int E0,
    const int* __restrict__ ei1, int E1,
    const unsigned char* __restrict__ bases,
    unsigned short* __restrict__ bins,
    int2* __restrict__ ovf, int* __restrict__ ovf_cnt)
{
    __shared__ int lcnt[SHARD_W];                       // 48.8 KB
    __shared__ __align__(16) unsigned char lbase[SHARD_W];  // 12.2 KB
    int q   = blockIdx.x & 3;
    int c   = (blockIdx.x >> 2) & (NCH - 1);
    int rel = blockIdx.x >> 8;
    const int* ei = rel ? ei1 : ei0;
    int E         = rel ? E1  : E0;
    int ce = (E + NCH - 1) / NCH;
    int lo = c * ce;
    int hi = min(lo + ce, E);
    int nlo = q * SHARD_W;

    const unsigned char* bsrc = bases + ((size_t)(rel * NCH + c)) * NN + nlo;
    for (int i = threadIdx.x; i < SHARD_W / 4; i += 256)
        ((unsigned*)lbase)[i] = ((const unsigned*)bsrc)[i];
    for (int i = threadIdx.x; i < SHARD_W; i += 256) lcnt[i] = 0;
    __syncthreads();

    int taskbase = rel * NN + nlo;
    for (int t = lo + threadIdx.x; t < hi; t += 256) {
        int loc = ei[E + t] - nlo;
        if ((unsigned)loc < (unsigned)SHARD_W) {
            int s = ei[t];
            int r = atomicAdd(&lcnt[loc], 1);
            int slot = (int)lbase[loc] + r;
            int task = taskbase + loc;
            if (slot < CAP) {
                bins[(size_t)task * CAP + slot] = (unsigned short)s;
            } else {
                int o = atomicAdd(ovf_cnt, 1);
                if (o < OVF_CAP) ovf[o] = make_int2(task, s);
            }
        }
    }
}

// One (rel,node) task per wave; paired bf16 gathers; inline overflow pickup.
// mean written in bf16 (one uint per lane) — agg consumed once by the GEMM.
__global__ __launch_bounds__(256) void aggregate(
    const unsigned short* __restrict__ bins, const int* __restrict__ deg,
    const unsigned short* __restrict__ hb, unsigned short* __restrict__ agg,
    const int2* __restrict__ ovf, const int* __restrict__ ovf_cnt)
{
    int lane = threadIdx.x & 63;
    int half = lane >> 5;
    int p = lane & 31;                 // feature-pair index
    int wid = (blockIdx.x * blockDim.x + threadIdx.x) >> 6;
    int nwaves = (gridDim.x * blockDim.x) >> 6;
    const unsigned int* hb32 = (const unsigned int*)hb;
    unsigned int* agg32 = (unsigned int*)agg;

    for (int task = wid; task < 2 * NN; task += nwaves) {
        int d = deg[task];
        int m = min(d, CAP);
        int idx = 0;
        if (lane < m) idx = bins[(size_t)task * CAP + lane];
        float a00=0.f,a01=0.f, a10=0.f,a11=0.f, a20=0.f,a21=0.f, a30=0.f,a31=0.f;
        int F = m >> 1;                // complete pair-steps
        int q = 0;
        for (; q + 4 <= F; q += 4) {
            int s0 = __shfl(idx, 2*(q+0) + half);
            int s1 = __shfl(idx, 2*(q+1) + half);
            int s2 = __shfl(idx, 2*(q+2) + half);
            int s3 = __shfl(idx, 2*(q+3) + half);
            unsigned u0 = hb32[(size_t)s0 * 32 + p];
            unsigned u1 = hb32[(size_t)s1 * 32 + p];
            unsigned u2 = hb32[(size_t)s2 * 32 + p];
            unsigned u3 = hb32[(size_t)s3 * 32 + p];
            a00 += __uint_as_float(u0 << 16); a01 += __uint_as_float(u0 & 0xffff0000u);
            a10 += __uint_as_float(u1 << 16); a11 += __uint_as_float(u1 & 0xffff0000u);
            a20 += __uint_as_float(u2 << 16); a21 += __uint_as_float(u2 & 0xffff0000u);
            a30 += __uint_as_float(u3 << 16); a31 += __uint_as_float(u3 & 0xffff0000u);
        }
        for (; q < F; ++q) {
            int s = __shfl(idx, 2*q + half);
            unsigned u = hb32[(size_t)s * 32 + p];
            a00 += __uint_as_float(u << 16); a01 += __uint_as_float(u & 0xffff0000u);
        }
        if (m & 1) {
            int s = __shfl(idx, m - 1);
            if (half == 0) {
                unsigned u = hb32[(size_t)s * 32 + p];
                a00 += __uint_as_float(u << 16); a01 += __uint_as_float(u & 0xffff0000u);
            }
        }
        if (d > CAP) {                 // rare: pick up this task's overflow edges
            int cnt = min(*ovf_cnt, OVF_CAP);
            for (int e = 0; e < cnt; ++e) {
                int2 v = ovf[e];
                if (v.x == task && half == 0) {
                    unsigned u = hb32[(size_t)v.y * 32 + p];
                    a00 += __uint_as_float(u << 16); a01 += __uint_as_float(u & 0xffff0000u);
                }
            }
        }
        float s0 = (a00 + a10) + (a20 + a30);
        float s1 = (a01 + a11) + (a21 + a31);
        s0 += __shfl_xor(s0, 32);
        s1 += __shfl_xor(s1, 32);
        if (half == 0) {
            float inv = 1.0f / (float)max(d, 1);
            unsigned lo = (unsigned)f2bf(s0 * inv);
            unsigned hi = (unsigned)f2bf(s1 * inv);
            agg32[(size_t)task * 32 + p] = lo | (hi << 16);
        }
    }
}

// L0: h1b = bf16( relu(mean0@Wl0 + mean1@Wl1 + self@(Wr0+Wr1) + b) ).
// All three K-chunks staged from bf16 sources. fp32 h1 is dead — removed.
#define RST 132
__global__ __launch_bounds__(256) void layer_gemm(
    const unsigned short* __restrict__ agg0, const unsigned short* __restrict__ agg1,
    const unsigned short* __restrict__ selfb,
    const float* __restrict__ Wl0, const float* __restrict__ Wl1,
    const float* __restrict__ Wr0, const float* __restrict__ Wr1,
    const float* __restrict__ b0, const float* __restrict__ b1,
    unsigned short* __restrict__ hb16)
{
    __shared__ float Wch[64 * 64];
    __shared__ float rowsT[64 * RST];
    __shared__ float bias[64];

    int tid = threadIdx.x;
    int base = blockIdx.x * 128;
    if (tid < 64) bias[tid] = b0[tid] + b1[tid];

    int j8 = (tid & 7) * 8;
    int n4 = (tid >> 3) * 4;

    float acc[4][8];
    #pragma unroll
    for (int i = 0; i < 4; i++)
        #pragma unroll
        for (int c = 0; c < 8; c++) acc[i][c] = 0.f;

    for (int chunk = 0; chunk < 3; chunk++) {
        const float* W = (chunk == 0) ? Wl0 : (chunk == 1) ? Wl1 : Wr0;
        const unsigned short* src = (chunk == 0) ? agg0 : (chunk == 1) ? agg1 : selfb;
        __syncthreads();
        #pragma unroll
        for (int r = 0; r < 4; r++) {
            int i = tid + 256 * r;
            float4 w = *(const float4*)&W[i * 4];
            if (chunk == 2) {
                float4 w2 = *(const float4*)&Wr1[i * 4];
                w.x += w2.x; w.y += w2.y; w.z += w2.z; w.w += w2.w;
            }
            *(float4*)&Wch[i * 4] = w;
        }
        #pragma unroll
        for (int r = 0; r < 8; r++) {
            int i = tid + 256 * r;
            int node = i >> 4;
            int k4 = (i & 15) * 4;
            int g = base + node;
            ushort4 u = make_ushort4(0, 0, 0, 0);
            if (g < NN) u = *(const ushort4*)&src[(size_t)g * 64 + k4];
            rowsT[(k4 + 0) * RST + node] = bf2f(u.x);
            rowsT[(k4 + 1) * RST + node] = bf2f(u.y);
            rowsT[(k4 + 2) * RST + node] = bf2f(u.z);
            rowsT[(k4 + 3) * RST + node] = bf2f(u.w);
        }
        __syncthreads();
        #pragma unroll 4
        for (int k = 0; k < 64; k++) {
            float4 wa = *(const float4*)&Wch[k * 64 + j8];
            float4 wb = *(const float4*)&Wch[k * 64 + j8 + 4];
            float4 rv = *(const float4*)&rowsT[k * RST + n4];
            float w[8] = {wa.x, wa.y, wa.z, wa.w, wb.x, wb.y, wb.z, wb.w};
            float rr[4] = {rv.x, rv.y, rv.z, rv.w};
            #pragma unroll
            for (int i = 0; i < 4; i++)
                #pragma unroll
                for (int c = 0; c < 8; c++)
                    acc[i][c] = fmaf(rr[i], w[c], acc[i][c]);
        }
    }

    #pragma unroll
    for (int i = 0; i < 4; i++) {
        int g = base + n4 + i;
        if (g < NN) {
            ushort4 p0, p1;
            p0.x = f2bf(fmaxf(acc[i][0] + bias[j8 + 0], 0.f));
            p0.y = f2bf(fmaxf(acc[i][1] + bias[j8 + 1], 0.f));
            p0.z = f2bf(fmaxf(acc[i][2] + bias[j8 + 2], 0.f));
            p0.w = f2bf(fmaxf(acc[i][3] + bias[j8 + 3], 0.f));
            p1.x = f2bf(fmaxf(acc[i][4] + bias[j8 + 4], 0.f));
            p1.y = f2bf(fmaxf(acc[i][5] + bias[j8 + 5], 0.f));
            p1.z = f2bf(fmaxf(acc[i][6] + bias[j8 + 6], 0.f));
            p1.w = f2bf(fmaxf(acc[i][7] + bias[j8 + 7], 0.f));
            *(ushort4*)&hb16[(size_t)g * 64 + j8]     = p0;
            *(ushort4*)&hb16[(size_t)g * 64 + j8 + 4] = p1;
        }
    }
}

// L1 + final fused: h2 tile in LDS, then out = h2 @ linW + linb.
__global__ __launch_bounds__(256) void layer_gemm_final(
    const unsigned short* __restrict__ agg0, const unsigned short* __restrict__ agg1,
    const unsigned short* __restrict__ selfb,
    const float* __restrict__ Wl0, const float* __restrict__ Wl1,
    const float* __restrict__ Wr0, const float* __restrict__ Wr1,
    const float* __restrict__ b0, const float* __restrict__ b1,
    const float* __restrict__ linW, const float* __restrict__ linb,
    float* __restrict__ out)
{
    __shared__ float Wch[64 * 64];
    __shared__ float rowsT[64 * RST];
    __shared__ float bias[64];

    int tid = threadIdx.x;
    int base = blockIdx.x * 128;
    if (tid < 64) bias[tid] = b0[tid] + b1[tid];

    int j8 = (tid & 7) * 8;
    int n4 = (tid >> 3) * 4;

    float acc[4][8];
    #pragma unroll
    for (int i = 0; i < 4; i++)
        #pragma unroll
        for (int c = 0; c < 8; c++) acc[i][c] = 0.f;

    for (int chunk = 0; chunk < 3; chunk++) {
        const float* W = (chunk == 0) ? Wl0 : (chunk == 1) ? Wl1 : Wr0;
        const unsigned short* src = (chunk == 0) ? agg0 : (chunk == 1) ? agg1 : selfb;
        __syncthreads();
        #pragma unroll
        for (int r = 0; r < 4; r++) {
            int i = tid + 256 * r;
            float4 w = *(const float4*)&W[i * 4];
            if (chunk == 2) {
                float4 w2 = *(const float4*)&Wr1[i * 4];
                w.x += w2.x; w.y += w2.y; w.z += w2.z; w.w += w2.w;
            }
            *(float4*)&Wch[i * 4] = w;
        }
        #pragma unroll
        for (int r = 0; r < 8; r++) {
            int i = tid + 256 * r;
            int node = i >> 4;
            int k4 = (i & 15) * 4;
            int g = base + node;
            ushort4 u = make_ushort4(0, 0, 0, 0);
            if (g < NN) u = *(const ushort4*)&src[(size_t)g * 64 + k4];
            rowsT[(k4 + 0) * RST + node] = bf2f(u.x);
            rowsT[(k4 + 1) * RST + node] = bf2f(u.y);
            rowsT[(k4 + 2) * RST + node] = bf2f(u.z);
            rowsT[(k4 + 3) * RST + node] = bf2f(u.w);
        }
        __syncthreads();
        #pragma unroll 4
        for (int k = 0; k < 64; k++) {
            float4 wa = *(const float4*)&Wch[k * 64 + j8];
            float4 wb = *(const float4*)&Wch[k * 64 + j8 + 4];
            float4 rv = *(const float4*)&rowsT[k * RST + n4];
            float w[8] = {wa.x, wa.y, wa.z, wa.w, wb.x, wb.y, wb.z, wb.w};
            float rr[4] = {rv.x, rv.y, rv.z, rv.w};
            #pragma unroll
            for (int i = 0; i < 4; i++)
                #pragma unroll
                for (int c = 0; c < 8; c++)
                    acc[i][c] = fmaf(rr[i], w[c], acc[i][c]);
        }
    }

    // relu epilogue into registers
    float o[4][8];
    #pragma unroll
    for (int i = 0; i < 4; i++)
        #pragma unroll
        for (int c = 0; c < 8; c++)
            o[i][c] = fmaxf(acc[i][c] + bias[j8 + c], 0.f);

    __syncthreads();   // everyone done reading Wch/rowsT/bias

    // restage: Wch <- linW (64x32), bias <- linb, rowsT <- h2 tile transposed
    #pragma unroll
    for (int r = 0; r < 2; r++) {
        int i = tid + 256 * r;   // 512 float4 = 2048 floats
        *(float4*)&Wch[i * 4] = *(const float4*)&linW[i * 4];
    }
    if (tid < 32) bias[tid] = linb[tid];
    #pragma unroll
    for (int i = 0; i < 4; i++)
        #pragma unroll
        for (int c = 0; c < 8; c++)
            rowsT[(j8 + c) * RST + (n4 + i)] = o[i][c];
    __syncthreads();

    // mini-GEMM: out[128 x 32] = h2_tile @ linW + linb
    int j4 = (tid & 7) * 4;
    float acc2[4][4];
    #pragma unroll
    for (int i = 0; i < 4; i++)
        #pragma unroll
        for (int c = 0; c < 4; c++) acc2[i][c] = 0.f;
    #pragma unroll 4
    for (int k = 0; k < 64; k++) {
        float4 w = *(const float4*)&Wch[k * 32 + j4];
        float4 rv = *(const float4*)&rowsT[k * RST + n4];
        float wr[4] = {w.x, w.y, w.z, w.w};
        float rr[4] = {rv.x, rv.y, rv.z, rv.w};
        #pragma unroll
        for (int i = 0; i < 4; i++)
            #pragma unroll
            for (int c = 0; c < 4; c++)
                acc2[i][c] = fmaf(rr[i], wr[c], acc2[i][c]);
    }
    #pragma unroll
    for (int i = 0; i < 4; i++) {
        int g = base + n4 + i;
        if (g < NN) {
            float4 ov;
            ov.x = acc2[i][0] + bias[j4 + 0];
            ov.y = acc2[i][1] + bias[j4 + 1];
            ov.z = acc2[i][2] + bias[j4 + 2];
            ov.w = acc2[i][3] + bias[j4 + 3];
            *(float4*)&out[(size_t)g * 32 + j4] = ov;
        }
    }
}

extern "C" void kernel_launch(void* const* d_in, const int* in_sizes, int n_in,
                              void* d_out, int out_size, void* d_ws, size_t ws_size,
                              hipStream_t stream)
{
    const float* x    = (const float*)d_in[0];
    const int*   ei0  = (const int*)d_in[1];
    const int*   ei1  = (const int*)d_in[2];
    const float* Wl   = (const float*)d_in[3];   // [2,2,64,64]
    const float* Wr   = (const float*)d_in[4];   // [2,2,64,64]
    const float* bl   = (const float*)d_in[5];   // [2,2,64]
    const float* linW = (const float*)d_in[6];   // [64,32]
    const float* linb = (const float*)d_in[7];   // [32]
    float* out = (float*)d_out;

    int E0 = in_sizes[1] / 2;
    int E1 = in_sizes[2] / 2;

    // Workspace (all bf16 intermediates; counting-sort scratch ALIASES dead
    // regions — zero extra footprint):
    // [bins 6.4MB | aggb 12.8MB | xb 6.4MB | h1b 6.4MB | deg 400KB | ovf] ~32.5MB
    //   cnt[2][NCH][NN] u8 (6.4MB)  aliases bins  (bins dead until place_pass)
    //   bases[2][NCH][NN] u8 (6.4MB) aliases aggb (aggb dead until aggregate)
    unsigned short* bins = (unsigned short*)d_ws;
    unsigned short* aggb = bins + (size_t)2 * NN * CAP;
    unsigned short* agg0 = aggb;
    unsigned short* agg1 = aggb + (size_t)NN * 64;
    unsigned short* xb   = aggb + (size_t)2 * NN * 64;
    unsigned short* h1b  = xb + (size_t)NN * 64;
    int*  deg     = (int*)(h1b + (size_t)NN * 64);
    int*  ovf_cnt = deg + 2 * NN;
    int2* ovf     = (int2*)(ovf_cnt + 8);
    unsigned char* cnt   = (unsigned char*)bins;
    unsigned char* bases = (unsigned char*)aggb;

    dim3 blk(256);
    int ggrid = (NN + 127) / 128;   // 391

    init_fuse<<<1024, blk, 0, stream>>>(x, xb, NN * 16, ovf_cnt, 8);

    // ---- LDS-atomic counting-sort binning (no global atomics on hot path) ----
    count_pass<<<2 * NCH * 4, blk, 0, stream>>>(ei0, E0, ei1, E1, cnt);
    prefix_pass<<<(2 * (NN / 4) + 255) / 256, blk, 0, stream>>>(cnt, bases, deg);
    place_pass<<<2 * NCH * 4, blk, 0, stream>>>(ei0, E0, ei1, E1, bases,
                                                bins, ovf, ovf_cnt);

    // ---- Layer 0 (gather + self from xb; h1b bf16 out) ----
    aggregate<<<4096, blk, 0, stream>>>(bins, deg, xb, aggb, ovf, ovf_cnt);
    layer_gemm<<<ggrid, blk, 0, stream>>>(agg0, agg1, xb,
        Wl + 0, Wl + 4096, Wr + 0, Wr + 4096, bl + 0, bl + 64, h1b);

    // ---- Layer 1 + final projection fused (h2 never materialized) ----
    aggregate<<<4096, blk, 0, stream>>>(bins, deg, h1b, aggb, ovf, ovf_cnt);
    layer_gemm_final<<<ggrid, blk, 0, stream>>>(agg0, agg1, h1b,
        Wl + 8192, Wl + 12288, Wr + 8192, Wr + 12288, bl + 128, bl + 192,
        linW, linb, out);
}

// Round 2
// 272.553 us; speedup vs baseline: 1.0212x; 1.0212x over previous
//
#include <hip/hip_runtime.h>

#define NN 50000
#define CAP 32          // per-node bin capacity; overflow handled correctly
#define OVF_CAP 4096
#define SHARD_W 6250    // node-eighth width (8 shards cover NN); R13: was 12500
#define NSH 8
#define NCH 64          // edge chunks per relation for counting sort

__device__ __forceinline__ unsigned short f2bf(float f) {
    unsigned u = __float_as_uint(f);
    u += 0x7fffu + ((u >> 16) & 1u);           // round-to-nearest-even
    return (unsigned short)(u >> 16);
}
__device__ __forceinline__ float bf2f(unsigned short u) {
    return __uint_as_float(((unsigned)u) << 16);
}

// Fused init: zero ovf_cnt AND convert x -> bf16.
__global__ __launch_bounds__(256) void init_fuse(
    const float* __restrict__ in, unsigned short* __restrict__ out, int n4,
    int* __restrict__ zbuf, int nint)
{
    int stride = gridDim.x * blockDim.x;
    int id0 = blockIdx.x * blockDim.x + threadIdx.x;
    for (int i = id0; i < n4; i += stride) {
        float4 v = ((const float4*)in)[i];
        ushort4 o;
        o.x = f2bf(v.x); o.y = f2bf(v.y); o.z = f2bf(v.z); o.w = f2bf(v.w);
        ((ushort4*)out)[i] = o;
    }
    for (int i = id0; i < nint; i += stride) zbuf[i] = 0;
}

// ---- Counting-sort binning, round 13 ----
// R12 counters: place_pass 47us @ Occupancy 16%, VALU 5%, HBM 14% => pure
// latency-bound, LDS-capped (61.5KB/block = 2 blocks/CU). Fix: pack LDS
// counters 2xu16-per-u32 (atomicAdd of 1<<16*parity; max 12500 adds/word so
// no cross-half carry) + 8 shards of 6250 => 18.75KB/block => ~6 blocks/CU.
//
// Block decode (grid = 2 rel * NCH chunks * NSH shards = 1024):
//   q = bid & 7, c = (bid>>3) & 63, rel = bid >> 9.

__global__ __launch_bounds__(256, 6) void count_pass(
    const int* __restrict__ ei0, int E0,
    const int* __restrict__ ei1, int E1,
    unsigned char* __restrict__ cnt)            // [2][NCH][NN] (aliases bins)
{
    __shared__ unsigned int lcnt32[SHARD_W / 2];   // packed 2xu16, 12.5KB
    int q   = blockIdx.x & (NSH - 1);
    int c   = (blockIdx.x >> 3) & (NCH - 1);
    int rel = blockIdx.x >> 9;
    const int* ei = rel ? ei1 : ei0;
    int E         = rel ? E1  : E0;
    int ce = (E + NCH - 1) / NCH;
    int lo = c * ce;
    int hi = min(lo + ce, E);
    int nlo = q * SHARD_W;

    for (int i = threadIdx.x; i < SHARD_W / 2; i += 256) lcnt32[i] = 0;
    __syncthreads();
    for (int t = lo + threadIdx.x; t < hi; t += 256) {
        int loc = ei[E + t] - nlo;
        if ((unsigned)loc < (unsigned)SHARD_W)
            atomicAdd(&lcnt32[loc >> 1], 1u << ((loc & 1) << 4));
    }
    __syncthreads();
    // nlo and plane base are even => ushort-aligned
    unsigned short* dst =
        (unsigned short*)(cnt + ((size_t)(rel * NCH + c)) * NN + nlo);
    for (int i = threadIdx.x; i < SHARD_W / 2; i += 256) {
        unsigned w = lcnt32[i];
        unsigned a = min(w & 0xffffu, 255u);
        unsigned b = min(w >> 16, 255u);
        dst[i] = (unsigned short)(a | (b << 8));
    }
}

// Per-node running sum over chunks: exact deg (int) + saturated u8 bases.
// Saturation is safe: only base values < CAP=32 ever index bins; any
// slot >= CAP goes to the overflow list regardless.
__global__ __launch_bounds__(256) void prefix_pass(
    const unsigned char* __restrict__ cnt,      // [2][NCH][NN]
    unsigned char* __restrict__ bases,          // [2][NCH][NN] (aliases aggb)
    int* __restrict__ deg)                      // [2*NN]
{
    int t = blockIdx.x * 256 + threadIdx.x;     // one thread per 4 nodes per rel
    if (t >= 2 * (NN / 4)) return;
    int rel = t / (NN / 4);
    int n4  = (t % (NN / 4)) * 4;

    unsigned run0 = 0, run1 = 0, run2 = 0, run3 = 0;
    #pragma unroll
    for (int c = 0; c < NCH; c++) {
        size_t idx = ((size_t)(rel * NCH + c)) * NN + n4;
        unsigned v = *(const unsigned*)&cnt[idx];
        unsigned b0 = min(run0, 255u), b1 = min(run1, 255u);
        unsigned b2 = min(run2, 255u), b3 = min(run3, 255u);
        *(unsigned*)&bases[idx] = b0 | (b1 << 8) | (b2 << 16) | (b3 << 24);
        run0 += v & 255u;
        run1 += (v >> 8) & 255u;
        run2 += (v >> 16) & 255u;
        run3 += (v >> 24);
    }
    *(int4*)&deg[rel * NN + n4] = make_int4(run0, run1, run2, run3);
}

__global__ __launch_bounds__(256, 6) void place_pass(
    const int* __restrict__ ei0, int E0,
    const int* __restrict__ ei1, int E1,
    const unsigned char* __restrict__ bases,
    unsigned short* __restrict__ bins,
    int2* __restrict__ ovf, int* __restrict__ ovf_cnt)
{
    __shared__ unsigned int lcnt32[SHARD_W / 2];       // 12.5KB
    __shared__ unsigned short lbase16[SHARD_W / 2];    // 6.25KB
    int q   = blockIdx.x & (NSH - 1);
    int c   = (blockIdx.x >> 3) & (NCH - 1);
    int rel = blockIdx.x >> 9;
    const int* ei = rel ? ei1 : ei0;
    int E         = rel ? E1  : E0;
    int ce = (E + NCH - 1) / NCH;
    int lo = c * ce;
    int hi = min(lo + ce, E);
    int nlo = q * SHARD_W;

    const unsigned short* bsrc =
        (const unsigned short*)(bases + ((size_t)(rel * NCH + c)) * NN + nlo);
    for (int i = threadIdx.x; i < SHARD_W / 2; i += 256) {
        lbase16[i] = bsrc[i];
        lcnt32[i] = 0;
    }
    __syncthreads();

    int taskbase = rel * NN + nlo;
    for (int t = lo + threadIdx.x; t < hi; t += 256) {
        int loc = ei[E + t] - nlo;
        if ((unsigned)loc < (unsigned)SHARD_W) {
            int s = ei[t];
            int sh = (loc & 1) << 4;
            unsigned r32 = atomicAdd(&lcnt32[loc >> 1], 1u << sh);
            int r = (int)((r32 >> sh) & 0xffffu);
            int b = (int)((lbase16[loc >> 1] >> ((loc & 1) << 3)) & 0xffu);
            int slot = b + r;
            int task = taskbase + loc;
            if (slot < CAP) {
                bins[(size_t)task * CAP + slot] = (unsigned short)s;
            } else {
                int o = atomicAdd(ovf_cnt, 1);
                if (o < OVF_CAP) ovf[o] = make_int2(task, s);
            }
        }
    }
}

// One (rel,node) task per wave; paired bf16 gathers; inline overflow pickup.
// mean written in bf16 (one uint per lane) — agg consumed once by the GEMM.
__global__ __launch_bounds__(256) void aggregate(
    const unsigned short* __restrict__ bins, const int* __restrict__ deg,
    const unsigned short* __restrict__ hb, unsigned short* __restrict__ agg,
    const int2* __restrict__ ovf, const int* __restrict__ ovf_cnt)
{
    int lane = threadIdx.x & 63;
    int half = lane >> 5;
    int p = lane & 31;                 // feature-pair index
    int wid = (blockIdx.x * blockDim.x + threadIdx.x) >> 6;
    int nwaves = (gridDim.x * blockDim.x) >> 6;
    const unsigned int* hb32 = (const unsigned int*)hb;
    unsigned int* agg32 = (unsigned int*)agg;

    for (int task = wid; task < 2 * NN; task += nwaves) {
        int d = deg[task];
        int m = min(d, CAP);
        int idx = 0;
        if (lane < m) idx = bins[(size_t)task * CAP + lane];
        float a00=0.f,a01=0.f, a10=0.f,a11=0.f, a20=0.f,a21=0.f, a30=0.f,a31=0.f;
        int F = m >> 1;                // complete pair-steps
        int q = 0;
        for (; q + 4 <= F; q += 4) {
            int s0 = __shfl(idx, 2*(q+0) + half);
            int s1 = __shfl(idx, 2*(q+1) + half);
            int s2 = __shfl(idx, 2*(q+2) + half);
            int s3 = __shfl(idx, 2*(q+3) + half);
            unsigned u0 = hb32[(size_t)s0 * 32 + p];
            unsigned u1 = hb32[(size_t)s1 * 32 + p];
            unsigned u2 = hb32[(size_t)s2 * 32 + p];
            unsigned u3 = hb32[(size_t)s3 * 32 + p];
            a00 += __uint_as_float(u0 << 16); a01 += __uint_as_float(u0 & 0xffff0000u);
            a10 += __uint_as_float(u1 << 16); a11 += __uint_as_float(u1 & 0xffff0000u);
            a20 += __uint_as_float(u2 << 16); a21 += __uint_as_float(u2 & 0xffff0000u);
            a30 += __uint_as_float(u3 << 16); a31 += __uint_as_float(u3 & 0xffff0000u);
        }
        for (; q < F; ++q) {
            int s = __shfl(idx, 2*q + half);
            unsigned u = hb32[(size_t)s * 32 + p];
            a00 += __uint_as_float(u << 16); a01 += __uint_as_float(u & 0xffff0000u);
        }
        if (m & 1) {
            int s = __shfl(idx, m - 1);
            if (half == 0) {
                unsigned u = hb32[(size_t)s * 32 + p];
                a00 += __uint_as_float(u << 16); a01 += __uint_as_float(u & 0xffff0000u);
            }
        }
        if (d > CAP) {                 // rare: pick up this task's overflow edges
            int cnt = min(*ovf_cnt, OVF_CAP);
            for (int e = 0; e < cnt; ++e) {
                int2 v = ovf[e];
                if (v.x == task && half == 0) {
                    unsigned u = hb32[(size_t)v.y * 32 + p];
                    a00 += __uint_as_float(u << 16); a01 += __uint_as_float(u & 0xffff0000u);
                }
            }
        }
        float s0 = (a00 + a10) + (a20 + a30);
        float s1 = (a01 + a11) + (a21 + a31);
        s0 += __shfl_xor(s0, 32);
        s1 += __shfl_xor(s1, 32);
        if (half == 0) {
            float inv = 1.0f / (float)max(d, 1);
            unsigned lo = (unsigned)f2bf(s0 * inv);
            unsigned hi = (unsigned)f2bf(s1 * inv);
            agg32[(size_t)task * 32 + p] = lo | (hi << 16);
        }
    }
}

// L0: h1b = bf16( relu(mean0@Wl0 + mean1@Wl1 + self@(Wr0+Wr1) + b) ).
// All three K-chunks staged from bf16 sources. fp32 h1 is dead — removed.
#define RST 132
__global__ __launch_bounds__(256) void layer_gemm(
    const unsigned short* __restrict__ agg0, const unsigned short* __restrict__ agg1,
    const unsigned short* __restrict__ selfb,
    const float* __restrict__ Wl0, const float* __restrict__ Wl1,
    const float* __restrict__ Wr0, const float* __restrict__ Wr1,
    const float* __restrict__ b0, const float* __restrict__ b1,
    unsigned short* __restrict__ hb16)
{
    __shared__ float Wch[64 * 64];
    __shared__ float rowsT[64 * RST];
    __shared__ float bias[64];

    int tid = threadIdx.x;
    int base = blockIdx.x * 128;
    if (tid < 64) bias[tid] = b0[tid] + b1[tid];

    int j8 = (tid & 7) * 8;
    int n4 = (tid >> 3) * 4;

    float acc[4][8];
    #pragma unroll
    for (int i = 0; i < 4; i++)
        #pragma unroll
        for (int c = 0; c < 8; c++) acc[i][c] = 0.f;

    for (int chunk = 0; chunk < 3; chunk++) {
        const float* W = (chunk == 0) ? Wl0 : (chunk == 1) ? Wl1 : Wr0;
        const unsigned short* src = (chunk == 0) ? agg0 : (chunk == 1) ? agg1 : selfb;
        __syncthreads();
        #pragma unroll
        for (int r = 0; r < 4; r++) {
            int i = tid + 256 * r;
            float4 w = *(const float4*)&W[i * 4];
            if (chunk == 2) {
                float4 w2 = *(const float4*)&Wr1[i * 4];
                w.x += w2.x; w.y += w2.y; w.z += w2.z; w.w += w2.w;
            }
            *(float4*)&Wch[i * 4] = w;
        }
        #pragma unroll
        for (int r = 0; r < 8; r++) {
            int i = tid + 256 * r;
            int node = i >> 4;
            int k4 = (i & 15) * 4;
            int g = base + node;
            ushort4 u = make_ushort4(0, 0, 0, 0);
            if (g < NN) u = *(const ushort4*)&src[(size_t)g * 64 + k4];
            rowsT[(k4 + 0) * RST + node] = bf2f(u.x);
            rowsT[(k4 + 1) * RST + node] = bf2f(u.y);
            rowsT[(k4 + 2) * RST + node] = bf2f(u.z);
            rowsT[(k4 + 3) * RST + node] = bf2f(u.w);
        }
        __syncthreads();
        #pragma unroll 4
        for (int k = 0; k < 64; k++) {
            float4 wa = *(const float4*)&Wch[k * 64 + j8];
            float4 wb = *(const float4*)&Wch[k * 64 + j8 + 4];
            float4 rv = *(const float4*)&rowsT[k * RST + n4];
            float w[8] = {wa.x, wa.y, wa.z, wa.w, wb.x, wb.y, wb.z, wb.w};
            float rr[4] = {rv.x, rv.y, rv.z, rv.w};
            #pragma unroll
            for (int i = 0; i < 4; i++)
                #pragma unroll
                for (int c = 0; c < 8; c++)
                    acc[i][c] = fmaf(rr[i], w[c], acc[i][c]);
        }
    }

    #pragma unroll
    for (int i = 0; i < 4; i++) {
        int g = base + n4 + i;
        if (g < NN) {
            ushort4 p0, p1;
            p0.x = f2bf(fmaxf(acc[i][0] + bias[j8 + 0], 0.f));
            p0.y = f2bf(fmaxf(acc[i][1] + bias[j8 + 1], 0.f));
            p0.z = f2bf(fmaxf(acc[i][2] + bias[j8 + 2], 0.f));
            p0.w = f2bf(fmaxf(acc[i][3] + bias[j8 + 3], 0.f));
            p1.x = f2bf(fmaxf(acc[i][4] + bias[j8 + 4], 0.f));
            p1.y = f2bf(fmaxf(acc[i][5] + bias[j8 + 5], 0.f));
            p1.z = f2bf(fmaxf(acc[i][6] + bias[j8 + 6], 0.f));
            p1.w = f2bf(fmaxf(acc[i][7] + bias[j8 + 7], 0.f));
            *(ushort4*)&hb16[(size_t)g * 64 + j8]     = p0;
            *(ushort4*)&hb16[(size_t)g * 64 + j8 + 4] = p1;
        }
    }
}

// L1 + final fused: h2 tile in LDS, then out = h2 @ linW + linb.
__global__ __launch_bounds__(256) void layer_gemm_final(
    const unsigned short* __restrict__ agg0, const unsigned short* __restrict__ agg1,
    const unsigned short* __restrict__ selfb,
    const float* __restrict__ Wl0, const float* __restrict__ Wl1,
    const float* __restrict__ Wr0, const float* __restrict__ Wr1,
    const float* __restrict__ b0, const float* __restrict__ b1,
    const float* __restrict__ linW, const float* __restrict__ linb,
    float* __restrict__ out)
{
    __shared__ float Wch[64 * 64];
    __shared__ float rowsT[64 * RST];
    __shared__ float bias[64];

    int tid = threadIdx.x;
    int base = blockIdx.x * 128;
    if (tid < 64) bias[tid] = b0[tid] + b1[tid];

    int j8 = (tid & 7) * 8;
    int n4 = (tid >> 3) * 4;

    float acc[4][8];
    #pragma unroll
    for (int i = 0; i < 4; i++)
        #pragma unroll
        for (int c = 0; c < 8; c++) acc[i][c] = 0.f;

    for (int chunk = 0; chunk < 3; chunk++) {
        const float* W = (chunk == 0) ? Wl0 : (chunk == 1) ? Wl1 : Wr0;
        const unsigned short* src = (chunk == 0) ? agg0 : (chunk == 1) ? agg1 : selfb;
        __syncthreads();
        #pragma unroll
        for (int r = 0; r < 4; r++) {
            int i = tid + 256 * r;
            float4 w = *(const float4*)&W[i * 4];
            if (chunk == 2) {
                float4 w2 = *(const float4*)&Wr1[i * 4];
                w.x += w2.x; w.y += w2.y; w.z += w2.z; w.w += w2.w;
            }
            *(float4*)&Wch[i * 4] = w;
        }
        #pragma unroll
        for (int r = 0; r < 8; r++) {
            int i = tid + 256 * r;
            int node = i >> 4;
            int k4 = (i & 15) * 4;
            int g = base + node;
            ushort4 u = make_ushort4(0, 0, 0, 0);
            if (g < NN) u = *(const ushort4*)&src[(size_t)g * 64 + k4];
            rowsT[(k4 + 0) * RST + node] = bf2f(u.x);
            rowsT[(k4 + 1) * RST + node] = bf2f(u.y);
            rowsT[(k4 + 2) * RST + node] = bf2f(u.z);
            rowsT[(k4 + 3) * RST + node] = bf2f(u.w);
        }
        __syncthreads();
        #pragma unroll 4
        for (int k = 0; k < 64; k++) {
            float4 wa = *(const float4*)&Wch[k * 64 + j8];
            float4 wb = *(const float4*)&Wch[k * 64 + j8 + 4];
            float4 rv = *(const float4*)&rowsT[k * RST + n4];
            float w[8] = {wa.x, wa.y, wa.z, wa.w, wb.x, wb.y, wb.z, wb.w};
            float rr[4] = {rv.x, rv.y, rv.z, rv.w};
            #pragma unroll
            for (int i = 0; i < 4; i++)
                #pragma unroll
                for (int c = 0; c < 8; c++)
                    acc[i][c] = fmaf(rr[i], w[c], acc[i][c]);
        }
    }

    // relu epilogue into registers
    float o[4][8];
    #pragma unroll
    for (int i = 0; i < 4; i++)
        #pragma unroll
        for (int c = 0; c < 8; c++)
            o[i][c] = fmaxf(acc[i][c] + bias[j8 + c], 0.f);

    __syncthreads();   // everyone done reading Wch/rowsT/bias

    // restage: Wch <- linW (64x32), bias <- linb, rowsT <- h2 tile transposed
    #pragma unroll
    for (int r = 0; r < 2; r++) {
        int i = tid + 256 * r;   // 512 float4 = 2048 floats
        *(float4*)&Wch[i * 4] = *(const float4*)&linW[i * 4];
    }
    if (tid < 32) bias[tid] = linb[tid];
    #pragma unroll
    for (int i = 0; i < 4; i++)
        #pragma unroll
        for (int c = 0; c < 8; c++)
            rowsT[(j8 + c) * RST + (n4 + i)] = o[i][c];
    __syncthreads();

    // mini-GEMM: out[128 x 32] = h2_tile @ linW + linb
    int j4 = (tid & 7) * 4;
    float acc2[4][4];
    #pragma unroll
    for (int i = 0; i < 4; i++)
        #pragma unroll
        for (int c = 0; c < 4; c++) acc2[i][c] = 0.f;
    #pragma unroll 4
    for (int k = 0; k < 64; k++) {
        float4 w = *(const float4*)&Wch[k * 32 + j4];
        float4 rv = *(const float4*)&rowsT[k * RST + n4];
        float wr[4] = {w.x, w.y, w.z, w.w};
        float rr[4] = {rv.x, rv.y, rv.z, rv.w};
        #pragma unroll
        for (int i = 0; i < 4; i++)
            #pragma unroll
            for (int c = 0; c < 4; c++)
                acc2[i][c] = fmaf(rr[i], wr[c], acc2[i][c]);
    }
    #pragma unroll
    for (int i = 0; i < 4; i++) {
        int g = base + n4 + i;
        if (g < NN) {
            float4 ov;
            ov.x = acc2[i][0] + bias[j4 + 0];
            ov.y = acc2[i][1] + bias[j4 + 1];
            ov.z = acc2[i][2] + bias[j4 + 2];
            ov.w = acc2[i][3] + bias[j4 + 3];
            *(float4*)&out[(size_t)g * 32 + j4] = ov;
        }
    }
}

extern "C" void kernel_launch(void* const* d_in, const int* in_sizes, int n_in,
                              void* d_out, int out_size, void* d_ws, size_t ws_size,
                              hipStream_t stream)
{
    const float* x    = (const float*)d_in[0];
    const int*   ei0  = (const int*)d_in[1];
    const int*   ei1  = (const int*)d_in[2];
    const float* Wl   = (const float*)d_in[3];   // [2,2,64,64]
    const float* Wr   = (const float*)d_in[4];   // [2,2,64,64]
    const float* bl   = (const float*)d_in[5];   // [2,2,64]
    const float* linW = (const float*)d_in[6];   // [64,32]
    const float* linb = (const float*)d_in[7];   // [32]
    float* out = (float*)d_out;

    int E0 = in_sizes[1] / 2;
    int E1 = in_sizes[2] / 2;

    // Workspace (all bf16 intermediates; counting-sort scratch ALIASES dead
    // regions — zero extra footprint):
    // [bins 6.4MB | aggb 12.8MB | xb 6.4MB | h1b 6.4MB | deg 400KB | ovf] ~32.5MB
    //   cnt[2][NCH][NN] u8 (6.4MB)  aliases bins  (bins dead until place_pass)
    //   bases[2][NCH][NN] u8 (6.4MB) aliases aggb (aggb dead until aggregate)
    unsigned short* bins = (unsigned short*)d_ws;
    unsigned short* aggb = bins + (size_t)2 * NN * CAP;
    unsigned short* agg0 = aggb;
    unsigned short* agg1 = aggb + (size_t)NN * 64;
    unsigned short* xb   = aggb + (size_t)2 * NN * 64;
    unsigned short* h1b  = xb + (size_t)NN * 64;
    int*  deg     = (int*)(h1b + (size_t)NN * 64);
    int*  ovf_cnt = deg + 2 * NN;
    int2* ovf     = (int2*)(ovf_cnt + 8);
    unsigned char* cnt   = (unsigned char*)bins;
    unsigned char* bases = (unsigned char*)aggb;

    dim3 blk(256);
    int ggrid = (NN + 127) / 128;   // 391

    init_fuse<<<1024, blk, 0, stream>>>(x, xb, NN * 16, ovf_cnt, 8);

    // ---- LDS-atomic counting-sort binning (no global atomics on hot path) ----
    count_pass<<<2 * NCH * NSH, blk, 0, stream>>>(ei0, E0, ei1, E1, cnt);
    prefix_pass<<<(2 * (NN / 4) + 255) / 256, blk, 0, stream>>>(cnt, bases, deg);
    place_pass<<<2 * NCH * NSH, blk, 0, stream>>>(ei0, E0, ei1, E1, bases,
                                                  bins, ovf, ovf_cnt);

    // ---- Layer 0 (gather + self from xb; h1b bf16 out) ----
    aggregate<<<4096, blk, 0, stream>>>(bins, deg, xb, aggb, ovf, ovf_cnt);
    layer_gemm<<<ggrid, blk, 0, stream>>>(agg0, agg1, xb,
        Wl + 0, Wl + 4096, Wr + 0, Wr + 4096, bl + 0, bl + 64, h1b);

    // ---- Layer 1 + final projection fused (h2 never materialized) ----
    aggregate<<<4096, blk, 0, stream>>>(bins, deg, h1b, aggb, ovf, ovf_cnt);
    layer_gemm_final<<<ggrid, blk, 0, stream>>>(agg0, agg1, h1b,
        Wl + 8192, Wl + 12288, Wr + 8192, Wr + 12288, bl + 128, bl + 192,
        linW, linb, out);
}

// Round 3
// 263.303 us; speedup vs baseline: 1.0571x; 1.0351x over previous
//
#include <hip/hip_runtime.h>

#define NN 50000
#define CAP 32          // per-node bin capacity; overflow handled correctly
#define OVF_CAP 4096
#define SHARD_W 6250    // node-eighth width (8 shards cover NN)
#define NSH 8
#define NCH 128         // R14: 64->128 — grid 2048 = 8 blocks/CU (LDS max);
                        // R13's 1024-block grid left occupancy grid-limited at 36%

__device__ __forceinline__ unsigned short f2bf(float f) {
    unsigned u = __float_as_uint(f);
    u += 0x7fffu + ((u >> 16) & 1u);           // round-to-nearest-even
    return (unsigned short)(u >> 16);
}
__device__ __forceinline__ float bf2f(unsigned short u) {
    return __uint_as_float(((unsigned)u) << 16);
}

// Fused init: zero ovf_cnt AND convert x -> bf16.
__global__ __launch_bounds__(256) void init_fuse(
    const float* __restrict__ in, unsigned short* __restrict__ out, int n4,
    int* __restrict__ zbuf, int nint)
{
    int stride = gridDim.x * blockDim.x;
    int id0 = blockIdx.x * blockDim.x + threadIdx.x;
    for (int i = id0; i < n4; i += stride) {
        float4 v = ((const float4*)in)[i];
        ushort4 o;
        o.x = f2bf(v.x); o.y = f2bf(v.y); o.z = f2bf(v.z); o.w = f2bf(v.w);
        ((ushort4*)out)[i] = o;
    }
    for (int i = id0; i < nint; i += stride) zbuf[i] = 0;
}

// ---- Counting-sort binning, round 14 ----
// R13 counters: place 46us @ Occ 36.6%, VALU 14%, 1.4 TB/s — grid (1024 blk =
// 4/CU) was the occupancy cap, not LDS (8/CU allowed). NCH=128 -> 2048 blocks.
// cnt planes now 12.8MB: alias [bins|h1b] (contiguous, both dead until after
// prefix_pass). bases (12.8MB) still aliases aggb exactly.
//
// Block decode (grid = 2 rel * NCH chunks * NSH shards = 2048):
//   q = bid & 7, c = (bid>>3) & 127, rel = bid >> 10.

__global__ __launch_bounds__(256, 6) void count_pass(
    const int* __restrict__ ei0, int E0,
    const int* __restrict__ ei1, int E1,
    unsigned char* __restrict__ cnt)            // [2][NCH][NN] (aliases bins+h1b)
{
    __shared__ unsigned int lcnt32[SHARD_W / 2];   // packed 2xu16, 12.5KB
    int q   = blockIdx.x & (NSH - 1);
    int c   = (blockIdx.x >> 3) & (NCH - 1);
    int rel = blockIdx.x >> 10;
    const int* ei = rel ? ei1 : ei0;
    int E         = rel ? E1  : E0;
    int ce = (E + NCH - 1) / NCH;
    int lo = c * ce;
    int hi = min(lo + ce, E);
    int nlo = q * SHARD_W;

    for (int i = threadIdx.x; i < SHARD_W / 2; i += 256) lcnt32[i] = 0;
    __syncthreads();
    for (int t = lo + threadIdx.x; t < hi; t += 256) {
        int loc = ei[E + t] - nlo;
        if ((unsigned)loc < (unsigned)SHARD_W)
            atomicAdd(&lcnt32[loc >> 1], 1u << ((loc & 1) << 4));
    }
    __syncthreads();
    // nlo and plane base are even => ushort-aligned
    unsigned short* dst =
        (unsigned short*)(cnt + ((size_t)(rel * NCH + c)) * NN + nlo);
    for (int i = threadIdx.x; i < SHARD_W / 2; i += 256) {
        unsigned w = lcnt32[i];
        unsigned a = min(w & 0xffffu, 255u);
        unsigned b = min(w >> 16, 255u);
        dst[i] = (unsigned short)(a | (b << 8));
    }
}

// Per-node running sum over chunks: exact deg (int) + saturated u8 bases.
// Saturation is safe: only base values < CAP=32 ever index bins; any
// slot >= CAP goes to the overflow list regardless.
__global__ __launch_bounds__(256) void prefix_pass(
    const unsigned char* __restrict__ cnt,      // [2][NCH][NN]
    unsigned char* __restrict__ bases,          // [2][NCH][NN] (aliases aggb)
    int* __restrict__ deg)                      // [2*NN]
{
    int t = blockIdx.x * 256 + threadIdx.x;     // one thread per 4 nodes per rel
    if (t >= 2 * (NN / 4)) return;
    int rel = t / (NN / 4);
    int n4  = (t % (NN / 4)) * 4;

    unsigned run0 = 0, run1 = 0, run2 = 0, run3 = 0;
    #pragma unroll 4
    for (int c = 0; c < NCH; c++) {
        size_t idx = ((size_t)(rel * NCH + c)) * NN + n4;
        unsigned v = *(const unsigned*)&cnt[idx];
        unsigned b0 = min(run0, 255u), b1 = min(run1, 255u);
        unsigned b2 = min(run2, 255u), b3 = min(run3, 255u);
        *(unsigned*)&bases[idx] = b0 | (b1 << 8) | (b2 << 16) | (b3 << 24);
        run0 += v & 255u;
        run1 += (v >> 8) & 255u;
        run2 += (v >> 16) & 255u;
        run3 += (v >> 24);
    }
    *(int4*)&deg[rel * NN + n4] = make_int4(run0, run1, run2, run3);
}

__global__ __launch_bounds__(256, 6) void place_pass(
    const int* __restrict__ ei0, int E0,
    const int* __restrict__ ei1, int E1,
    const unsigned char* __restrict__ bases,
    unsigned short* __restrict__ bins,
    int2* __restrict__ ovf, int* __restrict__ ovf_cnt)
{
    __shared__ unsigned int lcnt32[SHARD_W / 2];       // 12.5KB
    __shared__ unsigned short lbase16[SHARD_W / 2];    // 6.25KB
    int q   = blockIdx.x & (NSH - 1);
    int c   = (blockIdx.x >> 3) & (NCH - 1);
    int rel = blockIdx.x >> 10;
    const int* ei = rel ? ei1 : ei0;
    int E         = rel ? E1  : E0;
    int ce = (E + NCH - 1) / NCH;
    int lo = c * ce;
    int hi = min(lo + ce, E);
    int nlo = q * SHARD_W;

    const unsigned short* bsrc =
        (const unsigned short*)(bases + ((size_t)(rel * NCH + c)) * NN + nlo);
    for (int i = threadIdx.x; i < SHARD_W / 2; i += 256) {
        lbase16[i] = bsrc[i];
        lcnt32[i] = 0;
    }
    __syncthreads();

    int taskbase = rel * NN + nlo;
    for (int t = lo + threadIdx.x; t < hi; t += 256) {
        int loc = ei[E + t] - nlo;
        if ((unsigned)loc < (unsigned)SHARD_W) {
            int s = ei[t];
            int sh = (loc & 1) << 4;
            unsigned r32 = atomicAdd(&lcnt32[loc >> 1], 1u << sh);
            int r = (int)((r32 >> sh) & 0xffffu);
            int b = (int)((lbase16[loc >> 1] >> ((loc & 1) << 3)) & 0xffu);
            int slot = b + r;
            int task = taskbase + loc;
            if (slot < CAP) {
                bins[(size_t)task * CAP + slot] = (unsigned short)s;
            } else {
                int o = atomicAdd(ovf_cnt, 1);
                if (o < OVF_CAP) ovf[o] = make_int2(task, s);
            }
        }
    }
}

// One (rel,node) task per wave; paired bf16 gathers; inline overflow pickup.
// mean written in bf16 (one uint per lane) — agg consumed once by the GEMM.
__global__ __launch_bounds__(256) void aggregate(
    const unsigned short* __restrict__ bins, const int* __restrict__ deg,
    const unsigned short* __restrict__ hb, unsigned short* __restrict__ agg,
    const int2* __restrict__ ovf, const int* __restrict__ ovf_cnt)
{
    int lane = threadIdx.x & 63;
    int half = lane >> 5;
    int p = lane & 31;                 // feature-pair index
    int wid = (blockIdx.x * blockDim.x + threadIdx.x) >> 6;
    int nwaves = (gridDim.x * blockDim.x) >> 6;
    const unsigned int* hb32 = (const unsigned int*)hb;
    unsigned int* agg32 = (unsigned int*)agg;

    for (int task = wid; task < 2 * NN; task += nwaves) {
        int d = deg[task];
        int m = min(d, CAP);
        int idx = 0;
        if (lane < m) idx = bins[(size_t)task * CAP + lane];
        float a00=0.f,a01=0.f, a10=0.f,a11=0.f, a20=0.f,a21=0.f, a30=0.f,a31=0.f;
        int F = m >> 1;                // complete pair-steps
        int q = 0;
        for (; q + 4 <= F; q += 4) {
            int s0 = __shfl(idx, 2*(q+0) + half);
            int s1 = __shfl(idx, 2*(q+1) + half);
            int s2 = __shfl(idx, 2*(q+2) + half);
            int s3 = __shfl(idx, 2*(q+3) + half);
            unsigned u0 = hb32[(size_t)s0 * 32 + p];
            unsigned u1 = hb32[(size_t)s1 * 32 + p];
            unsigned u2 = hb32[(size_t)s2 * 32 + p];
            unsigned u3 = hb32[(size_t)s3 * 32 + p];
            a00 += __uint_as_float(u0 << 16); a01 += __uint_as_float(u0 & 0xffff0000u);
            a10 += __uint_as_float(u1 << 16); a11 += __uint_as_float(u1 & 0xffff0000u);
            a20 += __uint_as_float(u2 << 16); a21 += __uint_as_float(u2 & 0xffff0000u);
            a30 += __uint_as_float(u3 << 16); a31 += __uint_as_float(u3 & 0xffff0000u);
        }
        for (; q < F; ++q) {
            int s = __shfl(idx, 2*q + half);
            unsigned u = hb32[(size_t)s * 32 + p];
            a00 += __uint_as_float(u << 16); a01 += __uint_as_float(u & 0xffff0000u);
        }
        if (m & 1) {
            int s = __shfl(idx, m - 1);
            if (half == 0) {
                unsigned u = hb32[(size_t)s * 32 + p];
                a00 += __uint_as_float(u << 16); a01 += __uint_as_float(u & 0xffff0000u);
            }
        }
        if (d > CAP) {                 // rare: pick up this task's overflow edges
            int cnt = min(*ovf_cnt, OVF_CAP);
            for (int e = 0; e < cnt; ++e) {
                int2 v = ovf[e];
                if (v.x == task && half == 0) {
                    unsigned u = hb32[(size_t)v.y * 32 + p];
                    a00 += __uint_as_float(u << 16); a01 += __uint_as_float(u & 0xffff0000u);
                }
            }
        }
        float s0 = (a00 + a10) + (a20 + a30);
        float s1 = (a01 + a11) + (a21 + a31);
        s0 += __shfl_xor(s0, 32);
        s1 += __shfl_xor(s1, 32);
        if (half == 0) {
            float inv = 1.0f / (float)max(d, 1);
            unsigned lo = (unsigned)f2bf(s0 * inv);
            unsigned hi = (unsigned)f2bf(s1 * inv);
            agg32[(size_t)task * 32 + p] = lo | (hi << 16);
        }
    }
}

// L0: h1b = bf16( relu(mean0@Wl0 + mean1@Wl1 + self@(Wr0+Wr1) + b) ).
#define RST 132
__global__ __launch_bounds__(256) void layer_gemm(
    const unsigned short* __restrict__ agg0, const unsigned short* __restrict__ agg1,
    const unsigned short* __restrict__ selfb,
    const float* __restrict__ Wl0, const float* __restrict__ Wl1,
    const float* __restrict__ Wr0, const float* __restrict__ Wr1,
    const float* __restrict__ b0, const float* __restrict__ b1,
    unsigned short* __restrict__ hb16)
{
    __shared__ float Wch[64 * 64];
    __shared__ float rowsT[64 * RST];
    __shared__ float bias[64];

    int tid = threadIdx.x;
    int base = blockIdx.x * 128;
    if (tid < 64) bias[tid] = b0[tid] + b1[tid];

    int j8 = (tid & 7) * 8;
    int n4 = (tid >> 3) * 4;

    float acc[4][8];
    #pragma unroll
    for (int i = 0; i < 4; i++)
        #pragma unroll
        for (int c = 0; c < 8; c++) acc[i][c] = 0.f;

    for (int chunk = 0; chunk < 3; chunk++) {
        const float* W = (chunk == 0) ? Wl0 : (chunk == 1) ? Wl1 : Wr0;
        const unsigned short* src = (chunk == 0) ? agg0 : (chunk == 1) ? agg1 : selfb;
        __syncthreads();
        #pragma unroll
        for (int r = 0; r < 4; r++) {
            int i = tid + 256 * r;
            float4 w = *(const float4*)&W[i * 4];
            if (chunk == 2) {
                float4 w2 = *(const float4*)&Wr1[i * 4];
                w.x += w2.x; w.y += w2.y; w.z += w2.z; w.w += w2.w;
            }
            *(float4*)&Wch[i * 4] = w;
        }
        #pragma unroll
        for (int r = 0; r < 8; r++) {
            int i = tid + 256 * r;
            int node = i >> 4;
            int k4 = (i & 15) * 4;
            int g = base + node;
            ushort4 u = make_ushort4(0, 0, 0, 0);
            if (g < NN) u = *(const ushort4*)&src[(size_t)g * 64 + k4];
            rowsT[(k4 + 0) * RST + node] = bf2f(u.x);
            rowsT[(k4 + 1) * RST + node] = bf2f(u.y);
            rowsT[(k4 + 2) * RST + node] = bf2f(u.z);
            rowsT[(k4 + 3) * RST + node] = bf2f(u.w);
        }
        __syncthreads();
        #pragma unroll 4
        for (int k = 0; k < 64; k++) {
            float4 wa = *(const float4*)&Wch[k * 64 + j8];
            float4 wb = *(const float4*)&Wch[k * 64 + j8 + 4];
            float4 rv = *(const float4*)&rowsT[k * RST + n4];
            float w[8] = {wa.x, wa.y, wa.z, wa.w, wb.x, wb.y, wb.z, wb.w};
            float rr[4] = {rv.x, rv.y, rv.z, rv.w};
            #pragma unroll
            for (int i = 0; i < 4; i++)
                #pragma unroll
                for (int c = 0; c < 8; c++)
                    acc[i][c] = fmaf(rr[i], w[c], acc[i][c]);
        }
    }

    #pragma unroll
    for (int i = 0; i < 4; i++) {
        int g = base + n4 + i;
        if (g < NN) {
            ushort4 p0, p1;
            p0.x = f2bf(fmaxf(acc[i][0] + bias[j8 + 0], 0.f));
            p0.y = f2bf(fmaxf(acc[i][1] + bias[j8 + 1], 0.f));
            p0.z = f2bf(fmaxf(acc[i][2] + bias[j8 + 2], 0.f));
            p0.w = f2bf(fmaxf(acc[i][3] + bias[j8 + 3], 0.f));
            p1.x = f2bf(fmaxf(acc[i][4] + bias[j8 + 4], 0.f));
            p1.y = f2bf(fmaxf(acc[i][5] + bias[j8 + 5], 0.f));
            p1.z = f2bf(fmaxf(acc[i][6] + bias[j8 + 6], 0.f));
            p1.w = f2bf(fmaxf(acc[i][7] + bias[j8 + 7], 0.f));
            *(ushort4*)&hb16[(size_t)g * 64 + j8]     = p0;
            *(ushort4*)&hb16[(size_t)g * 64 + j8 + 4] = p1;
        }
    }
}

// L1 + final fused: h2 tile in LDS, then out = h2 @ linW + linb.
__global__ __launch_bounds__(256) void layer_gemm_final(
    const unsigned short* __restrict__ agg0, const unsigned short* __restrict__ agg1,
    const unsigned short* __restrict__ selfb,
    const float* __restrict__ Wl0, const float* __restrict__ Wl1,
    const float* __restrict__ Wr0, const float* __restrict__ Wr1,
    const float* __restrict__ b0, const float* __restrict__ b1,
    const float* __restrict__ linW, const float* __restrict__ linb,
    float* __restrict__ out)
{
    __shared__ float Wch[64 * 64];
    __shared__ float rowsT[64 * RST];
    __shared__ float bias[64];

    int tid = threadIdx.x;
    int base = blockIdx.x * 128;
    if (tid < 64) bias[tid] = b0[tid] + b1[tid];

    int j8 = (tid & 7) * 8;
    int n4 = (tid >> 3) * 4;

    float acc[4][8];
    #pragma unroll
    for (int i = 0; i < 4; i++)
        #pragma unroll
        for (int c = 0; c < 8; c++) acc[i][c] = 0.f;

    for (int chunk = 0; chunk < 3; chunk++) {
        const float* W = (chunk == 0) ? Wl0 : (chunk == 1) ? Wl1 : Wr0;
        const unsigned short* src = (chunk == 0) ? agg0 : (chunk == 1) ? agg1 : selfb;
        __syncthreads();
        #pragma unroll
        for (int r = 0; r < 4; r++) {
            int i = tid + 256 * r;
            float4 w = *(const float4*)&W[i * 4];
            if (chunk == 2) {
                float4 w2 = *(const float4*)&Wr1[i * 4];
                w.x += w2.x; w.y += w2.y; w.z += w2.z; w.w += w2.w;
            }
            *(float4*)&Wch[i * 4] = w;
        }
        #pragma unroll
        for (int r = 0; r < 8; r++) {
            int i = tid + 256 * r;
            int node = i >> 4;
            int k4 = (i & 15) * 4;
            int g = base + node;
            ushort4 u = make_ushort4(0, 0, 0, 0);
            if (g < NN) u = *(const ushort4*)&src[(size_t)g * 64 + k4];
            rowsT[(k4 + 0) * RST + node] = bf2f(u.x);
            rowsT[(k4 + 1) * RST + node] = bf2f(u.y);
            rowsT[(k4 + 2) * RST + node] = bf2f(u.z);
            rowsT[(k4 + 3) * RST + node] = bf2f(u.w);
        }
        __syncthreads();
        #pragma unroll 4
        for (int k = 0; k < 64; k++) {
            float4 wa = *(const float4*)&Wch[k * 64 + j8];
            float4 wb = *(const float4*)&Wch[k * 64 + j8 + 4];
            float4 rv = *(const float4*)&rowsT[k * RST + n4];
            float w[8] = {wa.x, wa.y, wa.z, wa.w, wb.x, wb.y, wb.z, wb.w};
            float rr[4] = {rv.x, rv.y, rv.z, rv.w};
            #pragma unroll
            for (int i = 0; i < 4; i++)
                #pragma unroll
                for (int c = 0; c < 8; c++)
                    acc[i][c] = fmaf(rr[i], w[c], acc[i][c]);
        }
    }

    // relu epilogue into registers
    float o[4][8];
    #pragma unroll
    for (int i = 0; i < 4; i++)
        #pragma unroll
        for (int c = 0; c < 8; c++)
            o[i][c] = fmaxf(acc[i][c] + bias[j8 + c], 0.f);

    __syncthreads();   // everyone done reading Wch/rowsT/bias

    // restage: Wch <- linW (64x32), bias <- linb, rowsT <- h2 tile transposed
    #pragma unroll
    for (int r = 0; r < 2; r++) {
        int i = tid + 256 * r;   // 512 float4 = 2048 floats
        *(float4*)&Wch[i * 4] = *(const float4*)&linW[i * 4];
    }
    if (tid < 32) bias[tid] = linb[tid];
    #pragma unroll
    for (int i = 0; i < 4; i++)
        #pragma unroll
        for (int c = 0; c < 8; c++)
            rowsT[(j8 + c) * RST + (n4 + i)] = o[i][c];
    __syncthreads();

    // mini-GEMM: out[128 x 32] = h2_tile @ linW + linb
    int j4 = (tid & 7) * 4;
    float acc2[4][4];
    #pragma unroll
    for (int i = 0; i < 4; i++)
        #pragma unroll
        for (int c = 0; c < 4; c++) acc2[i][c] = 0.f;
    #pragma unroll 4
    for (int k = 0; k < 64; k++) {
        float4 w = *(const float4*)&Wch[k * 32 + j4];
        float4 rv = *(const float4*)&rowsT[k * RST + n4];
        float wr[4] = {w.x, w.y, w.z, w.w};
        float rr[4] = {rv.x, rv.y, rv.z, rv.w};
        #pragma unroll
        for (int i = 0; i < 4; i++)
            #pragma unroll
            for (int c = 0; c < 4; c++)
                acc2[i][c] = fmaf(rr[i], wr[c], acc2[i][c]);
    }
    #pragma unroll
    for (int i = 0; i < 4; i++) {
        int g = base + n4 + i;
        if (g < NN) {
            float4 ov;
            ov.x = acc2[i][0] + bias[j4 + 0];
            ov.y = acc2[i][1] + bias[j4 + 1];
            ov.z = acc2[i][2] + bias[j4 + 2];
            ov.w = acc2[i][3] + bias[j4 + 3];
            *(float4*)&out[(size_t)g * 32 + j4] = ov;
        }
    }
}

extern "C" void kernel_launch(void* const* d_in, const int* in_sizes, int n_in,
                              void* d_out, int out_size, void* d_ws, size_t ws_size,
                              hipStream_t stream)
{
    const float* x    = (const float*)d_in[0];
    const int*   ei0  = (const int*)d_in[1];
    const int*   ei1  = (const int*)d_in[2];
    const float* Wl   = (const float*)d_in[3];   // [2,2,64,64]
    const float* Wr   = (const float*)d_in[4];   // [2,2,64,64]
    const float* bl   = (const float*)d_in[5];   // [2,2,64]
    const float* linW = (const float*)d_in[6];   // [64,32]
    const float* linb = (const float*)d_in[7];   // [32]
    float* out = (float*)d_out;

    int E0 = in_sizes[1] / 2;
    int E1 = in_sizes[2] / 2;

    // Workspace layout (R14): bins and h1b made CONTIGUOUS so the 12.8MB
    // cnt[2][128][NN] u8 plane aliases them (both dead until after prefix):
    // [bins 6.4MB | h1b 6.4MB | aggb 12.8MB | xb 6.4MB | deg 400KB | ovf]
    //   cnt   (12.8MB) aliases bins+h1b
    //   bases (12.8MB) aliases aggb exactly
    unsigned short* bins = (unsigned short*)d_ws;
    unsigned short* h1b  = bins + (size_t)2 * NN * CAP;
    unsigned short* aggb = h1b + (size_t)NN * 64;
    unsigned short* agg0 = aggb;
    unsigned short* agg1 = aggb + (size_t)NN * 64;
    unsigned short* xb   = aggb + (size_t)2 * NN * 64;
    int*  deg     = (int*)(xb + (size_t)NN * 64);
    int*  ovf_cnt = deg + 2 * NN;
    int2* ovf     = (int2*)(ovf_cnt + 8);
    unsigned char* cnt   = (unsigned char*)bins;
    unsigned char* bases = (unsigned char*)aggb;

    dim3 blk(256);
    int ggrid = (NN + 127) / 128;   // 391

    init_fuse<<<1024, blk, 0, stream>>>(x, xb, NN * 16, ovf_cnt, 8);

    // ---- LDS-atomic counting-sort binning (no global atomics on hot path) ----
    count_pass<<<2 * NCH * NSH, blk, 0, stream>>>(ei0, E0, ei1, E1, cnt);
    prefix_pass<<<(2 * (NN / 4) + 255) / 256, blk, 0, stream>>>(cnt, bases, deg);
    place_pass<<<2 * NCH * NSH, blk, 0, stream>>>(ei0, E0, ei1, E1, bases,
                                                  bins, ovf, ovf_cnt);

    // ---- Layer 0 (gather + self from xb; h1b bf16 out) ----
    aggregate<<<4096, blk, 0, stream>>>(bins, deg, xb, aggb, ovf, ovf_cnt);
    layer_gemm<<<ggrid, blk, 0, stream>>>(agg0, agg1, xb,
        Wl + 0, Wl + 4096, Wr + 0, Wr + 4096, bl + 0, bl + 64, h1b);

    // ---- Layer 1 + final projection fused (h2 never materialized) ----
    aggregate<<<4096, blk, 0, stream>>>(bins, deg, h1b, aggb, ovf, ovf_cnt);
    layer_gemm_final<<<ggrid, blk, 0, stream>>>(agg0, agg1, h1b,
        Wl + 8192, Wl + 12288, Wr + 8192, Wr + 12288, bl + 128, bl + 192,
        linW, linb, out);
}